// Round 7
// baseline (128.151 us; speedup 1.0000x reference)
//
#include <hip/hip_runtime.h>
#include <hip/hip_bf16.h>

#define SL     32768
#define EPS_LN 1e-5f

typedef unsigned short u16;
typedef __attribute__((ext_vector_type(8))) short bf16x8;
typedef __attribute__((ext_vector_type(4))) float f32x4;

#define MFMA16(a, b, c) __builtin_amdgcn_mfma_f32_16x16x32_bf16((a), (b), (c), 0, 0, 0)

__device__ inline u16 f2bf(float f) {
    __hip_bfloat16 h = __float2bfloat16(f);
    return *reinterpret_cast<u16*>(&h);
}
__device__ inline float bf2f(u16 u) {
    unsigned v = ((unsigned)u) << 16;
    float f;
    __builtin_memcpy(&f, &v, 4);
    return f;
}
__device__ inline uint4 pack8(float4 a, float4 b) {
    union { uint4 v; u16 u[8]; } U;
    U.u[0] = f2bf(a.x); U.u[1] = f2bf(a.y); U.u[2] = f2bf(a.z); U.u[3] = f2bf(a.w);
    U.u[4] = f2bf(b.x); U.u[5] = f2bf(b.y); U.u[6] = f2bf(b.z); U.u[7] = f2bf(b.w);
    return U.v;
}

// ---------------------------------------------------------------------------
// QKV via MFMA. grid 512 n-tiles(64). Block stages x once ([64n][128d] bf16),
// then loops 3 o-tiles of 128: stage w (fp32->bf16, L2-resident re-read),
// 32 MFMA/wave, write. T = float (pass 1) or u16 (pass 2) input.
// ---------------------------------------------------------------------------
template<typename T>
__global__ __launch_bounds__(256) void qkv_mfma(const T* __restrict__ in,
                                                const float* __restrict__ wq,
                                                const float* __restrict__ bq,
                                                u16* __restrict__ qkv) {
    __shared__ u16 wT[128][136];
    __shared__ u16 xT[64][136];
    __shared__ float bs[384];
    __shared__ u16 outT[128][72];
    const int n0 = blockIdx.x * 64;
    const int t = threadIdx.x;

    // stage x transposed [n][d]; contiguous-segment mapping (8 lanes/row)
    #pragma unroll
    for (int itr = 0; itr < 4; ++itr) {
        const int u = t + itr * 256;
        const int d = u >> 3, noct = u & 7;
        if constexpr (sizeof(T) == 4) {
            const float* src = (const float*)in + (size_t)d * SL + n0 + noct * 8;
            float4 f0 = *(const float4*)src;
            float4 f1 = *(const float4*)(src + 4);
            xT[noct * 8 + 0][d] = f2bf(f0.x);
            xT[noct * 8 + 1][d] = f2bf(f0.y);
            xT[noct * 8 + 2][d] = f2bf(f0.z);
            xT[noct * 8 + 3][d] = f2bf(f0.w);
            xT[noct * 8 + 4][d] = f2bf(f1.x);
            xT[noct * 8 + 5][d] = f2bf(f1.y);
            xT[noct * 8 + 6][d] = f2bf(f1.z);
            xT[noct * 8 + 7][d] = f2bf(f1.w);
        } else {
            union { uint4 v; u16 s[8]; } U;
            U.v = *(const uint4*)((const u16*)in + (size_t)d * SL + n0 + noct * 8);
            #pragma unroll
            for (int j = 0; j < 8; ++j) xT[noct * 8 + j][d] = U.s[j];
        }
    }
    for (int i = t; i < 384; i += 256) bs[i] = bq[i];

    const int lane = t & 63, wv = t >> 6, lo = lane & 15, hi = lane >> 4;

    for (int ot = 0; ot < 3; ++ot) {
        const int o0 = ot * 128;
        if (ot) __syncthreads();   // prior store done before overwriting wT/outT
        // stage w [o][k] fp32 -> bf16, coalesced (8 lanes x 16 elems per row)
        #pragma unroll
        for (int itr = 0; itr < 4; ++itr) {
            const int o = itr * 32 + (t >> 3);
            const int f = (t & 7) * 16;
            const float* src = wq + (size_t)(o0 + o) * 128 + f;
            float4 a = *(const float4*)src;
            float4 b = *(const float4*)(src + 4);
            float4 c = *(const float4*)(src + 8);
            float4 d2 = *(const float4*)(src + 12);
            *(uint4*)&wT[o][f] = pack8(a, b);
            *(uint4*)&wT[o][f + 8] = pack8(c, d2);
        }
        __syncthreads();

        bf16x8 af[2][4];
        #pragma unroll
        for (int om = 0; om < 2; ++om)
            #pragma unroll
            for (int ks = 0; ks < 4; ++ks)
                af[om][ks] = *(const bf16x8*)&wT[wv * 32 + om * 16 + lo][hi * 8 + ks * 32];

        #pragma unroll
        for (int nt = 0; nt < 4; ++nt) {
            bf16x8 bfr[4];
            #pragma unroll
            for (int ks = 0; ks < 4; ++ks)
                bfr[ks] = *(const bf16x8*)&xT[nt * 16 + lo][hi * 8 + ks * 32];
            #pragma unroll
            for (int om = 0; om < 2; ++om) {
                f32x4 acc = {0.f, 0.f, 0.f, 0.f};
                #pragma unroll
                for (int ks = 0; ks < 4; ++ks)
                    acc = MFMA16(af[om][ks], bfr[ks], acc);
                #pragma unroll
                for (int r = 0; r < 4; ++r) {
                    const int orow = wv * 32 + om * 16 + hi * 4 + r;
                    outT[orow][nt * 16 + lo] = f2bf(acc[r] + bs[o0 + orow]);
                }
            }
        }
        __syncthreads();
        {   // coalesced store: 64 B per thread
            const int o = t >> 1, nh = (t & 1) * 32;
            u16* dst = qkv + (size_t)(o0 + o) * SL + n0 + nh;
            const uint4* s4 = (const uint4*)&outT[o][nh];
            #pragma unroll
            for (int k = 0; k < 4; ++k) ((uint4*)dst)[k] = s4[k];
        }
    }
}

// ---------------------------------------------------------------------------
// Fused attention via MFMA. K/V staged ONCE per (h,outer); inner loop over
// IT i-tiles of 64 queries. Output (bf16) overlays the Q/P LDS region.
// ---------------------------------------------------------------------------
template<int KLEN>
__global__ __launch_bounds__(256) void attn_kernel(const u16* __restrict__ qkv,
                                                   u16* __restrict__ ao) {
    constexpr int NJT = KLEN / 16;
    constexpr int JSEG = KLEN / 8;
    constexpr int IT = (KLEN == 256) ? 4 : 2;
    constexpr int NOUT = SL / KLEN;
    __shared__ u16 KT[KLEN][40];
    __shared__ u16 VT[32][KLEN + 8];
    __shared__ u16 QP[2][64][40];   // [0]=QT, [1]=PT; output overlays

    const int bid = blockIdx.x;
    const int outer = bid % NOUT;
    const int h = bid / NOUT;
    const int base = outer * KLEN;
    const int t = threadIdx.x;

    #pragma unroll
    for (int itr = 0; itr < KLEN / 64; ++itr) {   // K transposed [j][c]
        const int u0 = t + itr * 256;
        const int c = u0 / JSEG, jseg = u0 % JSEG;
        union { uint4 v; u16 s[8]; } u;
        u.v = *(const uint4*)(qkv + (size_t)(128 + h * 32 + c) * SL + base + jseg * 8);
        #pragma unroll
        for (int j = 0; j < 8; ++j) KT[jseg * 8 + j][c] = u.s[j];
    }
    #pragma unroll
    for (int itr = 0; itr < KLEN / 64; ++itr) {   // V native [c][j]
        const int u0 = t + itr * 256;
        const int c = u0 / JSEG, jseg = u0 % JSEG;
        *(uint4*)&VT[c][jseg * 8] =
            *(const uint4*)(qkv + (size_t)(256 + h * 32 + c) * SL + base + jseg * 8);
    }

    const int lane = t & 63, wv = t >> 6, lo = lane & 15, hi = lane >> 4;

    for (int it = 0; it < IT; ++it) {
        const int i0 = it * 64;
        if (it) __syncthreads();   // prior store reads done before QT overwrite
        {   // stage Q transposed [i][c], contiguous segments
            const int c = t >> 3, iseg = t & 7;
            union { uint4 v; u16 s[8]; } u;
            u.v = *(const uint4*)(qkv + (size_t)(h * 32 + c) * SL + base + i0 + iseg * 8);
            #pragma unroll
            for (int j = 0; j < 8; ++j) QP[0][iseg * 8 + j][c] = u.s[j];
        }
        __syncthreads();   // Q (and, on it=0, K/V) ready

        bf16x8 qfrag = *(const bf16x8*)&QP[0][wv * 16 + lo][hi * 8];
        f32x4 oacc0 = {0.f, 0.f, 0.f, 0.f}, oacc1 = {0.f, 0.f, 0.f, 0.f};
        float lsum[4] = {0.f, 0.f, 0.f, 0.f};

        #pragma unroll
        for (int jt = 0; jt < NJT; ++jt) {
            bf16x8 kfrag = *(const bf16x8*)&KT[jt * 16 + lo][hi * 8];
            f32x4 z = {0.f, 0.f, 0.f, 0.f};
            f32x4 s = MFMA16(qfrag, kfrag, z);
            #pragma unroll
            for (int r = 0; r < 4; ++r) {
                float p = __expf(s[r]);
                lsum[r] += p;
                QP[1][wv * 16 + hi * 4 + r][(jt & 1) * 16 + lo] = f2bf(p);
            }
            if (jt & 1) {
                bf16x8 pfrag = *(const bf16x8*)&QP[1][wv * 16 + lo][hi * 8];
                const int jb = (jt - 1) * 16;
                bf16x8 v0 = *(const bf16x8*)&VT[lo][jb + hi * 8];
                bf16x8 v1 = *(const bf16x8*)&VT[16 + lo][jb + hi * 8];
                oacc0 = MFMA16(pfrag, v0, oacc0);
                oacc1 = MFMA16(pfrag, v1, oacc1);
            }
        }
        #pragma unroll
        for (int r = 0; r < 4; ++r) {
            float v = lsum[r];
            v += __shfl_xor(v, 1);
            v += __shfl_xor(v, 2);
            v += __shfl_xor(v, 4);
            v += __shfl_xor(v, 8);
            lsum[r] = 1.f / v;
        }
        __syncthreads();   // all waves done with QP before output overlay
        u16 (*OTu)[72] = (u16 (*)[72])&QP[0][0][0];   // [32 d][64 i]
        #pragma unroll
        for (int r = 0; r < 4; ++r) {
            OTu[lo][wv * 16 + hi * 4 + r]      = f2bf(oacc0[r] * lsum[r]);
            OTu[16 + lo][wv * 16 + hi * 4 + r] = f2bf(oacc1[r] * lsum[r]);
        }
        __syncthreads();
        {   // coalesced store
            const int d = t >> 3, seg = t & 7;
            u16* dst = ao + (size_t)(h * 32 + d) * SL + base + i0 + seg * 8;
            *(uint4*)dst = *(uint4*)&OTu[d][seg * 8];
        }
    }
}

// ---------------------------------------------------------------------------
// stats: per-position mean/rstd of in0(T0) + in1(bf16). grid 256 x 128.
// ---------------------------------------------------------------------------
template<typename T0>
__global__ __launch_bounds__(128) void stats_kernel(const T0* __restrict__ in0,
                                                    const u16* __restrict__ in1,
                                                    float2* __restrict__ stats) {
    const int t = threadIdx.x;
    const int w = t >> 6, lane = t & 63;
    const int q = lane >> 4, pl = lane & 15;
    const int p = blockIdx.x * 128 + w * 64 + pl * 4;
    const T0* b0 = in0 + (size_t)q * 32 * SL + p;
    const u16* b1 = in1 + (size_t)q * 32 * SL + p;

    float s[4] = {0.f, 0.f, 0.f, 0.f};
    float ss[4] = {0.f, 0.f, 0.f, 0.f};
    #pragma unroll 4
    for (int dd = 0; dd < 32; ++dd) {
        float v[4];
        if constexpr (sizeof(T0) == 4) {
            float4 f = *(const float4*)(b0 + (size_t)dd * SL);
            v[0] = f.x; v[1] = f.y; v[2] = f.z; v[3] = f.w;
        } else {
            ushort4 h = *(const ushort4*)(b0 + (size_t)dd * SL);
            v[0] = bf2f(h.x); v[1] = bf2f(h.y); v[2] = bf2f(h.z); v[3] = bf2f(h.w);
        }
        ushort4 h1 = *(const ushort4*)(b1 + (size_t)dd * SL);
        v[0] += bf2f(h1.x); v[1] += bf2f(h1.y); v[2] += bf2f(h1.z); v[3] += bf2f(h1.w);
        #pragma unroll
        for (int k = 0; k < 4; ++k) { s[k] += v[k]; ss[k] += v[k] * v[k]; }
    }
    #pragma unroll
    for (int k = 0; k < 4; ++k) {
        s[k]  += __shfl_xor(s[k], 16);
        s[k]  += __shfl_xor(s[k], 32);
        ss[k] += __shfl_xor(ss[k], 16);
        ss[k] += __shfl_xor(ss[k], 32);
    }
    if (q == 0) {
        #pragma unroll
        for (int k = 0; k < 4; ++k) {
            const float mean = s[k] * (1.f / 128.f);
            const float var  = ss[k] * (1.f / 128.f) - mean * mean;
            stats[p + k] = make_float2(mean, rsqrtf(var + EPS_LN));
        }
    }
}

// ---------------------------------------------------------------------------
// apply: normalize + transpose. T0 = residual type, TO = output type.
// ---------------------------------------------------------------------------
template<int NIN, typename T0, typename TO>
__global__ __launch_bounds__(256) void apply_kernel(const T0* __restrict__ in0,
                                                    const u16* __restrict__ in1,
                                                    const float2* __restrict__ stats,
                                                    const float* __restrict__ g,
                                                    const float* __restrict__ be,
                                                    TO* __restrict__ outp) {
    constexpr int NOUT = SL / NIN;
    constexpr int RT = NOUT / 16;
    constexpr int CT = NIN / 16;
    __shared__ float sm[16][16][17];
    __shared__ float2 st[16][16];
    const int bid = blockIdx.x;
    const int dc  = bid / (RT * CT);
    const int rem = bid % (RT * CT);
    const int r0 = (rem / CT) * 16;
    const int c0 = (rem % CT) * 16;
    const int t = threadIdx.x;

    {
        const int r = t >> 4, c = t & 15;
        st[r][c] = stats[(r0 + r) * NIN + c0 + c];
    }
    __syncthreads();

    const int d16 = t >> 4;
    const int d = dc * 16 + d16;
    const float gd = g[d], bd = be[d];
    {
        const int r = t & 15;
        float fv[16];
        if constexpr (sizeof(T0) == 4) {
            const float* p0 = (const float*)in0 + (size_t)d * SL + (r0 + r) * NIN + c0;
            #pragma unroll
            for (int k = 0; k < 4; ++k) *(float4*)&fv[k * 4] = *(const float4*)(p0 + k * 4);
        } else {
            const u16* p0 = (const u16*)in0 + (size_t)d * SL + (r0 + r) * NIN + c0;
            union { uint4 v[2]; u16 u[16]; } A;
            A.v[0] = *(const uint4*)p0;
            A.v[1] = *(const uint4*)(p0 + 8);
            #pragma unroll
            for (int c = 0; c < 16; ++c) fv[c] = bf2f(A.u[c]);
        }
        const u16* p1 = in1 + (size_t)d * SL + (r0 + r) * NIN + c0;
        union { uint4 v[2]; u16 u[16]; } B;
        B.v[0] = *(const uint4*)p1;
        B.v[1] = *(const uint4*)(p1 + 8);
        #pragma unroll
        for (int c = 0; c < 16; ++c) {
            const float v = fv[c] + bf2f(B.u[c]);
            const float2 mz = st[r][c];
            sm[d16][c][r] = (v - mz.x) * mz.y * gd + bd;
        }
    }
    __syncthreads();
    {
        const int c = t & 15;
        float ov[16];
        #pragma unroll
        for (int k = 0; k < 4; ++k) *(float4*)&ov[k * 4] = *(const float4*)&sm[d16][c][k * 4];
        if constexpr (sizeof(TO) == 4) {
            float* dst = (float*)outp + (size_t)d * SL + (c0 + c) * NOUT + r0;
            #pragma unroll
            for (int k = 0; k < 4; ++k) *(float4*)(dst + k * 4) = *(const float4*)&ov[k * 4];
        } else {
            u16* dst = (u16*)outp + (size_t)d * SL + (c0 + c) * NOUT + r0;
            union { uint4 v[2]; u16 u[16]; } O;
            #pragma unroll
            for (int k = 0; k < 16; ++k) O.u[k] = f2bf(ov[k]);
            *(uint4*)dst = O.v[0];
            *(uint4*)(dst + 8) = O.v[1];
        }
    }
}

// ---------------------------------------------------------------------------
extern "C" void kernel_launch(void* const* d_in, const int* in_sizes, int n_in,
                              void* d_out, int out_size, void* d_ws, size_t ws_size,
                              hipStream_t stream) {
    const float* x     = (const float*)d_in[0];
    const float* w_row = (const float*)d_in[1];
    const float* b_row = (const float*)d_in[2];
    const float* w_col = (const float*)d_in[3];
    const float* b_col = (const float*)d_in[4];
    const float* g1    = (const float*)d_in[5];
    const float* be1   = (const float*)d_in[6];
    const float* g2    = (const float*)d_in[7];
    const float* be2   = (const float*)d_in[8];
    float* out = (float*)d_out;

    // ws: qkv 24MB | ao 8MB | o1b 8MB | stats 256KB
    char* base = (char*)d_ws;
    u16*    qkvb  = (u16*)base;                       base += (size_t)384 * SL * 2;
    u16*    ao16  = (u16*)base;                       base += (size_t)128 * SL * 2;
    u16*    o1b   = (u16*)base;                       base += (size_t)128 * SL * 2;
    float2* stats = (float2*)base;

    qkv_mfma<float><<<512, 256, 0, stream>>>(x, w_row, b_row, qkvb);
    attn_kernel<256><<<512, 256, 0, stream>>>(qkvb, ao16);
    stats_kernel<float><<<256, 128, 0, stream>>>(x, ao16, stats);
    apply_kernel<256, float, u16><<<1024, 256, 0, stream>>>(x, ao16, stats, g1, be1, o1b);
    qkv_mfma<u16><<<512, 256, 0, stream>>>(o1b, w_col, b_col, qkvb);
    attn_kernel<128><<<1024, 256, 0, stream>>>(qkvb, ao16);
    stats_kernel<u16><<<256, 128, 0, stream>>>(o1b, ao16, stats);
    apply_kernel<128, u16, float><<<1024, 256, 0, stream>>>(o1b, ao16, stats, g2, be2, out);
}